// Round 4
// baseline (314.508 us; speedup 1.0000x reference)
//
#include <hip/hip_runtime.h>
#include <stdint.h>

typedef unsigned short u16;
typedef unsigned int u32;
typedef __attribute__((ext_vector_type(8))) short short8;
typedef __attribute__((ext_vector_type(4))) float floatx4;

#define BATCH   131072
#define NA      3
#define OBS     30
#define ACTD    9
#define HID     128
#define HEADS   4
#define HD      32
#define MB      16
#define ROWS    (MB*NA)     // 48
#define LDC     136         // padded row stride
#define QSCALE  0.17677669529663687f

// prepacked-weight offsets in d_ws, u16 units (fragment = 64 lanes x 8 bf16)
#define OFF_WO    0
#define OFF_WOA   12288
#define OFF_WQ    36864
#define OFF_WK    53248
#define OFF_WV    69632
#define OFF_WC1   86016
#define OFF_WC2   184320
#define PRE_TOTAL 190464

union S8 { short8 s; u32 w[4]; };

__device__ __forceinline__ u16 f2bf(float f) {
    union { float f; u32 u; } v; v.f = f;
    return (u16)((v.u + 0x8000u) >> 16);
}
__device__ __forceinline__ u32 pk_bf16(float a, float b) {
    union { float f; u32 u; } x, y; x.f = a; y.f = b;
    return ((x.u + 0x8000u) >> 16) | ((y.u + 0x8000u) & 0xffff0000u);
}
__device__ __forceinline__ float lo16f(u32 w) { union { u32 u; float f; } v; v.u = w << 16; return v.f; }
__device__ __forceinline__ float hi16f(u32 w) { union { u32 u; float f; } v; v.u = w & 0xffff0000u; return v.f; }
__device__ __forceinline__ float leaky(float x) { return x >= 0.f ? x : 0.01f * x; }

// ------------- weight prepack: f32 [k][n] -> bf16 fragment order (A/B symmetric) -------------
__global__ void prepack_kernel(const float* __restrict__ Wo,  const float* __restrict__ Woa,
                               const float* __restrict__ Wq,  const float* __restrict__ Wk,
                               const float* __restrict__ Wv,  const float* __restrict__ Wc1,
                               const float* __restrict__ Wc2, u16* __restrict__ out) {
    int i = blockIdx.x * blockDim.x + threadIdx.x;
    if (i >= PRE_TOTAL) return;
    const float* src; int K, KT, perA, base, Nsrc, Nlim; float scl = 1.f;
    if (i < OFF_WOA)      { src = Wo;  K = 30;  KT = 1; perA = 4096;  base = OFF_WO;  Nsrc = 128; Nlim = 128; }
    else if (i < OFF_WQ)  { src = Woa; K = 39;  KT = 2; perA = 8192;  base = OFF_WOA; Nsrc = 128; Nlim = 128; }
    else if (i < OFF_WK)  { src = Wq;  K = 128; KT = 4; perA = 16384; base = OFF_WQ;  Nsrc = 128; Nlim = 128; scl = QSCALE; }
    else if (i < OFF_WV)  { src = Wk;  K = 128; KT = 4; perA = 16384; base = OFF_WK;  Nsrc = 128; Nlim = 128; }
    else if (i < OFF_WC1) { src = Wv;  K = 128; KT = 4; perA = 16384; base = OFF_WV;  Nsrc = 128; Nlim = 128; }
    else if (i < OFF_WC2) { src = Wc1; K = 256; KT = 8; perA = 32768; base = OFF_WC1; Nsrc = 128; Nlim = 128; }
    else                  { src = Wc2; K = 128; KT = 4; perA = 2048;  base = OFF_WC2; Nsrc = 9;   Nlim = 9;   }
    int j = i - base;
    int agent = j / perA;
    int r = j - agent * perA;
    int e = r & 7, lane = (r >> 3) & 63, fk = r >> 9;
    int kt = fk % KT, nt = fk / KT;
    int n = nt * 16 + (lane & 15);
    int k = kt * 32 + (lane >> 4) * 8 + e;
    u16 v = 0;
    if (k < K && n < Nlim) v = f2bf(src[(agent * K + k) * Nsrc + n] * scl);
    out[i] = v;
}

// ---------------- fused forward ----------------
// Operand-swapped MFMA everywhere: D = W_frag(A) x Act_frag(B) -> D[row=feature][col=batch];
// epilogues write 4 consecutive features per lane as one b64.
__global__ __launch_bounds__(256, 3) void fused_kernel(
    const float* __restrict__ obs, const float* __restrict__ act,
    const float* __restrict__ b_o, const float* __restrict__ b_oa,
    const float* __restrict__ bq,  const float* __restrict__ bk_, const float* __restrict__ bv,
    const float* __restrict__ bc1, const float* __restrict__ bc2,
    const u16* __restrict__ pre, float* __restrict__ out)
{
    __shared__ __align__(16) u16 s_mem[4 * ROWS * LDC];        // 52224 B
    __shared__ float2 s_probs[MB * HEADS * NA];                // 1536 B (total 53760 -> 3 blk/CU)
    u16* s_oemb  = s_mem;                    // o_emb (persistent to stage4)
    u16* s_oaemb = s_mem + ROWS * LDC;       // oa_emb -> attn_out
    u16* s_bufA  = s_mem + 2 * ROWS * LDC;   // Q -> V
    u16* s_bufB  = s_mem + 3 * ROWS * LDC;   // K -> h

    const int tid  = threadIdx.x;
    const int wave = tid >> 6, lane = tid & 63;
    const int l15  = lane & 15, quad = lane >> 4;
    const int b0   = blockIdx.x * MB;
    const short8* preV = (const short8*)pre;

    // ---- stage 1: per-agent embeds; activation B-frags built straight from global f32 ----
    for (int sj = wave; sj < 12; sj += 4) {
        int oa = sj / 6;                 // 0: o_emb  1: oa_emb
        int rem = sj % 6, agent = rem >> 1, nh = rem & 1;
        const float* obs_row = obs + ((size_t)(b0 + l15) * NA + agent) * OBS;
        const float* act_row = act + ((size_t)(b0 + l15) * NA + agent) * ACTD;
        float a0 = oa ? act_row[0] : 0.f;
        float a1 = oa ? act_row[1] : 0.f;
        // kt=0 frag: k = quad*8 + {0..7}; k<30 from obs, k==30/31 from act (oa only)
        S8 f0;
        #pragma unroll
        for (int p = 0; p < 4; p++) {
            int k = quad * 8 + 2 * p;
            bool inobs = k < 30;
            float2 ov = *(const float2*)(obs_row + (inobs ? k : 0));
            float va = inobs ? ov.x : a0;    // k==30 is the only non-obs slot in kt0
            float vb = inobs ? ov.y : a1;
            f0.w[p] = pk_bf16(va, vb);
        }
        // kt=1 frag (oa only): k = 32+quad*8+j -> act[2+j] valid for quad==0, j<7
        S8 f1;
        if (oa) {
            #pragma unroll
            for (int p = 0; p < 4; p++) {
                int j0 = 2 * p;
                float va = (quad == 0 && j0 < 7) ? act_row[2 + j0] : 0.f;
                float vb = (quad == 0 && j0 + 1 < 7) ? act_row[3 + j0] : 0.f;
                f1.w[p] = pk_bf16(va, vb);
            }
        }
        int KT = oa ? 2 : 1;
        int preBase = oa ? (OFF_WOA / 8 + agent * 1024) : (OFF_WO / 8 + agent * 512);
        floatx4 acc[4] = {};
        #pragma unroll
        for (int n4 = 0; n4 < 4; n4++) {
            int nt = nh * 4 + n4;
            acc[n4] = __builtin_amdgcn_mfma_f32_16x16x32_bf16(preV[preBase + (nt * KT + 0) * 64 + lane], f0.s, acc[n4], 0, 0, 0);
            if (oa)
                acc[n4] = __builtin_amdgcn_mfma_f32_16x16x32_bf16(preV[preBase + (nt * KT + 1) * 64 + lane], f1.s, acc[n4], 0, 0, 0);
        }
        u16* dst = oa ? s_oaemb : s_oemb;
        const float* bias = (oa ? b_oa : b_o) + agent * HID;
        int r = l15 * NA + agent;
        #pragma unroll
        for (int n4 = 0; n4 < 4; n4++) {
            int nb = (nh * 4 + n4) * 16 + quad * 4;
            float4 bb = *(const float4*)&bias[nb];
            uint2 w;
            w.x = pk_bf16(leaky(acc[n4][0] + bb.x), leaky(acc[n4][1] + bb.y));
            w.y = pk_bf16(leaky(acc[n4][2] + bb.z), leaky(acc[n4][3] + bb.w));
            *(uint2*)&dst[r * LDC + nb] = w;
        }
    }
    __syncthreads();

    // ---- stage 2: Q (scale folded into Wq) and K; weight frags register-cached across mt ----
    {
        int proj = wave >> 1, nh = wave & 1;   // w0/w1: Q, w2/w3: K
        const u16* Abuf = proj ? s_oaemb : s_oemb;
        int preBase = (proj ? OFF_WK : OFF_WQ) / 8;
        u16* dst = proj ? s_bufB : s_bufA;
        const float* bias = proj ? bk_ : bq;
        float bscl = proj ? 1.f : QSCALE;
        short8 wf[16];
        #pragma unroll
        for (int n4 = 0; n4 < 4; n4++)
            #pragma unroll
            for (int kt = 0; kt < 4; kt++)
                wf[n4 * 4 + kt] = preV[preBase + ((nh * 4 + n4) * 4 + kt) * 64 + lane];
        for (int mt = 0; mt < 3; mt++) {
            short8 xa[4];
            #pragma unroll
            for (int kt = 0; kt < 4; kt++)
                xa[kt] = *(const short8*)&Abuf[(mt * 16 + l15) * LDC + kt * 32 + quad * 8];
            floatx4 acc[4] = {};
            #pragma unroll
            for (int n4 = 0; n4 < 4; n4++)
                #pragma unroll
                for (int kt = 0; kt < 4; kt++)
                    acc[n4] = __builtin_amdgcn_mfma_f32_16x16x32_bf16(wf[n4 * 4 + kt], xa[kt], acc[n4], 0, 0, 0);
            int r = mt * 16 + l15;
            #pragma unroll
            for (int n4 = 0; n4 < 4; n4++) {
                int nb = (nh * 4 + n4) * 16 + quad * 4;
                float4 bb = *(const float4*)&bias[nb];
                uint2 w;
                w.x = pk_bf16(acc[n4][0] + bb.x * bscl, acc[n4][1] + bb.y * bscl);
                w.y = pk_bf16(acc[n4][2] + bb.z * bscl, acc[n4][3] + bb.w * bscl);
                *(uint2*)&dst[r * LDC + nb] = w;
            }
        }
    }
    __syncthreads();

    // ---- stage 3a: masked softmax, off-diagonal only ----
    if (tid < MB * HEADS * NA) {
        int e = tid / (HEADS * NA), r = tid - e * HEADS * NA, h = r / NA, n = r - h * NA;
        int m0 = (n == 0) ? 1 : 0;
        int m1 = (n == 2) ? 1 : 2;
        const uint4* qp = (const uint4*)&s_bufA[(e * NA + n) * LDC + h * HD];
        const uint4* kp0 = (const uint4*)&s_bufB[(e * NA + m0) * LDC + h * HD];
        const uint4* kp1 = (const uint4*)&s_bufB[(e * NA + m1) * LDC + h * HD];
        float s0 = 0.f, s1 = 0.f;
        #pragma unroll
        for (int c = 0; c < 4; c++) {
            uint4 qw = qp[c], aw = kp0[c], bw = kp1[c];
            u32 qv[4] = {qw.x, qw.y, qw.z, qw.w};
            u32 av[4] = {aw.x, aw.y, aw.z, aw.w};
            u32 bv_[4] = {bw.x, bw.y, bw.z, bw.w};
            #pragma unroll
            for (int j = 0; j < 4; j++) {
                float ql = lo16f(qv[j]), qh = hi16f(qv[j]);
                s0 += ql * lo16f(av[j]) + qh * hi16f(av[j]);
                s1 += ql * lo16f(bv_[j]) + qh * hi16f(bv_[j]);
            }
        }
        float mx = fmaxf(s0, s1);
        float p0 = __expf(s0 - mx), p1 = __expf(s1 - mx);
        float inv = 1.f / (p0 + p1);
        s_probs[(e * HEADS + h) * NA + n] = make_float2(p0 * inv, p1 * inv);
    }
    __syncthreads();

    // ---- stage 3b: V = oa_emb @ Wv + bv ; frags cached, mt loop ----
    {
        int np = wave;   // 0..3, 2 nt each
        short8 wf[8];
        #pragma unroll
        for (int n2 = 0; n2 < 2; n2++)
            #pragma unroll
            for (int kt = 0; kt < 4; kt++)
                wf[n2 * 4 + kt] = preV[OFF_WV / 8 + ((np * 2 + n2) * 4 + kt) * 64 + lane];
        for (int mt = 0; mt < 3; mt++) {
            short8 xa[4];
            #pragma unroll
            for (int kt = 0; kt < 4; kt++)
                xa[kt] = *(const short8*)&s_oaemb[(mt * 16 + l15) * LDC + kt * 32 + quad * 8];
            floatx4 acc[2] = {};
            #pragma unroll
            for (int n2 = 0; n2 < 2; n2++)
                #pragma unroll
                for (int kt = 0; kt < 4; kt++)
                    acc[n2] = __builtin_amdgcn_mfma_f32_16x16x32_bf16(wf[n2 * 4 + kt], xa[kt], acc[n2], 0, 0, 0);
            int r = mt * 16 + l15;
            #pragma unroll
            for (int n2 = 0; n2 < 2; n2++) {
                int nb = (np * 2 + n2) * 16 + quad * 4;
                float4 bb = *(const float4*)&bv[nb];
                uint2 w;
                w.x = pk_bf16(acc[n2][0] + bb.x, acc[n2][1] + bb.y);
                w.y = pk_bf16(acc[n2][2] + bb.z, acc[n2][3] + bb.w);
                *(uint2*)&s_bufA[r * LDC + nb] = w;
            }
        }
    }
    __syncthreads();

    // ---- stage 3c: attn_out = probs @ V ----
    if (tid < MB * HEADS * NA) {
        int e = tid / (HEADS * NA), r = tid - e * HEADS * NA, h = r / NA, n = r - h * NA;
        int m0 = (n == 0) ? 1 : 0;
        int m1 = (n == 2) ? 1 : 2;
        float2 p = s_probs[(e * HEADS + h) * NA + n];
        const uint4* v0p = (const uint4*)&s_bufA[(e * NA + m0) * LDC + h * HD];
        const uint4* v1p = (const uint4*)&s_bufA[(e * NA + m1) * LDC + h * HD];
        uint4* dst = (uint4*)&s_oaemb[(e * NA + n) * LDC + h * HD];
        #pragma unroll
        for (int c = 0; c < 4; c++) {
            uint4 aw = v0p[c], bw = v1p[c], ow;
            u32 av[4] = {aw.x, aw.y, aw.z, aw.w};
            u32 bv_[4] = {bw.x, bw.y, bw.z, bw.w};
            u32 ov[4];
            #pragma unroll
            for (int j = 0; j < 4; j++) {
                float lo = p.x * lo16f(av[j]) + p.y * lo16f(bv_[j]);
                float hi = p.x * hi16f(av[j]) + p.y * hi16f(bv_[j]);
                ov[j] = pk_bf16(lo, hi);
            }
            ow.x = ov[0]; ow.y = ov[1]; ow.z = ov[2]; ow.w = ov[3];
            dst[c] = ow;
        }
    }
    __syncthreads();

    // ---- stage 4: critic layer 1, K-split concat (kt<4: o_emb, kt>=4: attn_out) ----
    for (int sj = wave; sj < 12; sj += 4) {
        int agent = sj >> 2, nq = sj & 3;
        int r = l15 * NA + agent;
        short8 xa[8];
        #pragma unroll
        for (int kt = 0; kt < 8; kt++) {
            const u16* A = (kt < 4) ? s_oemb : s_oaemb;
            xa[kt] = *(const short8*)&A[r * LDC + (kt & 3) * 32 + quad * 8];
        }
        floatx4 acc[2] = {};
        #pragma unroll
        for (int n2 = 0; n2 < 2; n2++)
            #pragma unroll
            for (int kt = 0; kt < 8; kt++) {
                short8 wfr = preV[OFF_WC1 / 8 + agent * 4096 + ((nq * 2 + n2) * 8 + kt) * 64 + lane];
                acc[n2] = __builtin_amdgcn_mfma_f32_16x16x32_bf16(wfr, xa[kt], acc[n2], 0, 0, 0);
            }
        #pragma unroll
        for (int n2 = 0; n2 < 2; n2++) {
            int nb = (nq * 2 + n2) * 16 + quad * 4;
            float4 bb = *(const float4*)&bc1[agent * HID + nb];
            uint2 w;
            w.x = pk_bf16(leaky(acc[n2][0] + bb.x), leaky(acc[n2][1] + bb.y));
            w.y = pk_bf16(leaky(acc[n2][2] + bb.z), leaky(acc[n2][3] + bb.w));
            *(uint2*)&s_bufB[r * LDC + nb] = w;
        }
    }
    __syncthreads();

    // ---- stage 5: critic layer 2 -> q_values, f32 out (row=action n, col=batch) ----
    if (wave < NA) {
        int agent = wave;
        int r = l15 * NA + agent;
        floatx4 acc = {};
        #pragma unroll
        for (int kt = 0; kt < 4; kt++) {
            short8 xa = *(const short8*)&s_bufB[r * LDC + kt * 32 + quad * 8];
            acc = __builtin_amdgcn_mfma_f32_16x16x32_bf16(preV[OFF_WC2 / 8 + agent * 256 + kt * 64 + lane], xa, acc, 0, 0, 0);
        }
        #pragma unroll
        for (int rg = 0; rg < 4; rg++) {
            int n = quad * 4 + rg;
            if (n < ACTD)
                out[((size_t)(b0 + l15) * NA + agent) * ACTD + n] = acc[rg] + bc2[agent * ACTD + n];
        }
    }
}

extern "C" void kernel_launch(void* const* d_in, const int* in_sizes, int n_in,
                              void* d_out, int out_size, void* d_ws, size_t ws_size,
                              hipStream_t stream) {
    const float* obs = (const float*)d_in[0];
    const float* act = (const float*)d_in[1];
    const float* Wo  = (const float*)d_in[2];
    const float* bo  = (const float*)d_in[3];
    const float* Woa = (const float*)d_in[4];
    const float* boa = (const float*)d_in[5];
    const float* Wq  = (const float*)d_in[6];
    const float* bq  = (const float*)d_in[7];
    const float* Wk  = (const float*)d_in[8];
    const float* bk  = (const float*)d_in[9];
    const float* Wv  = (const float*)d_in[10];
    const float* bv  = (const float*)d_in[11];
    const float* Wc1 = (const float*)d_in[12];
    const float* bc1 = (const float*)d_in[13];
    const float* Wc2 = (const float*)d_in[14];
    const float* bc2 = (const float*)d_in[15];
    u16* pre = (u16*)d_ws;   // needs 380928 B of workspace

    prepack_kernel<<<(PRE_TOTAL + 255) / 256, 256, 0, stream>>>(Wo, Woa, Wq, Wk, Wv, Wc1, Wc2, pre);
    fused_kernel<<<BATCH / MB, 256, 0, stream>>>(obs, act, bo, boa, bq, bk, bv, bc1, bc2, pre,
                                                 (float*)d_out);
}

// Round 5
// 273.731 us; speedup vs baseline: 1.1490x; 1.1490x over previous
//
#include <hip/hip_runtime.h>
#include <stdint.h>

typedef unsigned short u16;
typedef unsigned int u32;
typedef __attribute__((ext_vector_type(8))) short short8;
typedef __attribute__((ext_vector_type(4))) float floatx4;

#define BATCH   131072
#define NA      3
#define OBS     30
#define ACTD    9
#define HID     128
#define HEADS   4
#define HD      32
#define MB      16
#define ROWS    (MB*NA)     // 48
#define LDC     136         // padded row stride
#define LDOA    72          // oa input tile stride
#define QSCALE  0.17677669529663687f

// prepacked-weight offsets in d_ws, u16 units (fragment = 64 lanes x 8 bf16)
#define OFF_WO    0
#define OFF_WOA   12288
#define OFF_WQ    36864
#define OFF_WK    53248
#define OFF_WV    69632
#define OFF_WC1   86016
#define OFF_WC2   184320
#define PRE_TOTAL 190464

__device__ __forceinline__ u16 f2bf(float f) {          // round-nearest (ties up)
    union { float f; u32 u; } v; v.f = f;
    return (u16)((v.u + 0x8000u) >> 16);
}
__device__ __forceinline__ u32 pk_bf16(float a, float b) {
    union { float f; u32 u; } x, y; x.f = a; y.f = b;
    return ((x.u + 0x8000u) >> 16) | ((y.u + 0x8000u) & 0xffff0000u);
}
__device__ __forceinline__ float lo16f(u32 w) { union { u32 u; float f; } v; v.u = w << 16; return v.f; }
__device__ __forceinline__ float hi16f(u32 w) { union { u32 u; float f; } v; v.u = w & 0xffff0000u; return v.f; }
__device__ __forceinline__ float leaky(float x) { return x >= 0.f ? x : 0.01f * x; }

// ------------- weight prepack: f32 [k][n] -> bf16 MFMA B-fragment order -------------
__global__ void prepack_kernel(const float* __restrict__ Wo,  const float* __restrict__ Woa,
                               const float* __restrict__ Wq,  const float* __restrict__ Wk,
                               const float* __restrict__ Wv,  const float* __restrict__ Wc1,
                               const float* __restrict__ Wc2, u16* __restrict__ out) {
    int i = blockIdx.x * blockDim.x + threadIdx.x;
    if (i >= PRE_TOTAL) return;
    const float* src; int K, KT, perA, base, Nsrc, Nlim; float scl = 1.f;
    if (i < OFF_WOA)      { src = Wo;  K = 30;  KT = 1; perA = 4096;  base = OFF_WO;  Nsrc = 128; Nlim = 128; }
    else if (i < OFF_WQ)  { src = Woa; K = 39;  KT = 2; perA = 8192;  base = OFF_WOA; Nsrc = 128; Nlim = 128; }
    else if (i < OFF_WK)  { src = Wq;  K = 128; KT = 4; perA = 16384; base = OFF_WQ;  Nsrc = 128; Nlim = 128; scl = QSCALE; }
    else if (i < OFF_WV)  { src = Wk;  K = 128; KT = 4; perA = 16384; base = OFF_WK;  Nsrc = 128; Nlim = 128; }
    else if (i < OFF_WC1) { src = Wv;  K = 128; KT = 4; perA = 16384; base = OFF_WV;  Nsrc = 128; Nlim = 128; }
    else if (i < OFF_WC2) { src = Wc1; K = 256; KT = 8; perA = 32768; base = OFF_WC1; Nsrc = 128; Nlim = 128; }
    else                  { src = Wc2; K = 128; KT = 4; perA = 2048;  base = OFF_WC2; Nsrc = 9;   Nlim = 9;   }
    int j = i - base;
    int agent = j / perA;
    int r = j - agent * perA;
    int e = r & 7, lane = (r >> 3) & 63, fk = r >> 9;
    int kt = fk % KT, nt = fk / KT;
    int n = nt * 16 + (lane & 15);
    int k = kt * 32 + (lane >> 4) * 8 + e;
    u16 v = 0;
    if (k < K && n < Nlim) v = f2bf(src[(agent * K + k) * Nsrc + n] * scl);
    out[i] = v;
}

// ---------------- fused forward (R3 structure + cached weight frags + reg-probs) ----------------
__global__ __launch_bounds__(256, 3) void fused_kernel(
    const float* __restrict__ obs, const float* __restrict__ act,
    const float* __restrict__ b_o, const float* __restrict__ b_oa,
    const float* __restrict__ bq,  const float* __restrict__ bk_, const float* __restrict__ bv,
    const float* __restrict__ bc1, const float* __restrict__ bc2,
    const u16* __restrict__ pre, float* __restrict__ out)
{
    __shared__ __align__(16) u16 s_mem[4 * ROWS * LDC];        // 52224 B total -> 3 blk/CU
    u16* s_oemb  = s_mem;                    // o_emb (persistent)
    u16* s_oaemb = s_mem + ROWS * LDC;       // oa_emb -> attn_out
    u16* s_bufA  = s_mem + 2 * ROWS * LDC;   // oa-tile -> Q -> V
    u16* s_bufB  = s_mem + 3 * ROWS * LDC;   // K -> h

    const int tid  = threadIdx.x;
    const int wave = tid >> 6, lane = tid & 63;
    const int l15  = lane & 15, quad = lane >> 4;
    const int b0   = blockIdx.x * MB;
    const short8* preV = (const short8*)pre;

    // ---- stage 0: stage [obs|act|0] tile as packed u32 writes, layout [agent][MB][LDOA] ----
    for (int g = tid; g < ROWS * 15; g += 256) {               // obs k=0..29
        int r = g / 15, s = g - r * 15;
        int n = r / MB, bl = r - n * MB;
        const float* src = &obs[((b0 + bl) * NA + n) * OBS + 2 * s];
        *(u32*)&s_bufA[n * (MB * LDOA) + bl * LDOA + 2 * s] = pk_bf16(src[0], src[1]);
    }
    for (int g = tid; g < ROWS * 5; g += 256) {                // act k=30..38, zero k=39
        int r = g / 5, s = g - r * 5;
        int n = r / MB, bl = r - n * MB;
        const float* src = &act[((b0 + bl) * NA + n) * ACTD + 2 * s];
        float v0 = src[0], v1 = (s < 4) ? src[1] : 0.f;
        *(u32*)&s_bufA[n * (MB * LDOA) + bl * LDOA + 30 + 2 * s] = pk_bf16(v0, v1);
    }
    for (int g = tid; g < ROWS * 12; g += 256) {               // zero k=40..63
        int r = g / 12, s = g - r * 12;
        int n = r / MB, bl = r - n * MB;
        *(u32*)&s_bufA[n * (MB * LDOA) + bl * LDOA + 40 + 2 * s] = 0;
    }
    __syncthreads();

    // ---- stage 1: per-agent embeds ----
    for (int sj = wave; sj < 12; sj += 4) {
        int osel = sj / 6;              // 0: o_emb  1: oa_emb
        int rem = sj % 6, agent = rem >> 1, nh = rem & 1;
        int KTn = osel ? 2 : 1;
        const float* bias = osel ? b_oa : b_o;
        int preBase = osel ? (OFF_WOA / 8 + agent * 1024) : (OFF_WO / 8 + agent * 512);
        floatx4 acc[4] = {};
        for (int kt = 0; kt < KTn; kt++) {
            short8 a = *(const short8*)&s_bufA[agent * (MB * LDOA) + l15 * LDOA + kt * 32 + quad * 8];
            for (int n4 = 0; n4 < 4; n4++) {
                int nt = nh * 4 + n4;
                short8 b = preV[preBase + (nt * KTn + kt) * 64 + lane];
                acc[n4] = __builtin_amdgcn_mfma_f32_16x16x32_bf16(a, b, acc[n4], 0, 0, 0);
            }
        }
        u16* dst = osel ? s_oaemb : s_oemb;
        for (int n4 = 0; n4 < 4; n4++) {
            int col = (nh * 4 + n4) * 16 + l15;
            float bb = bias[agent * HID + col];
            for (int rg = 0; rg < 4; rg++) {
                int m = quad * 4 + rg;
                dst[(m * NA + agent) * LDC + col] = f2bf(leaky(acc[n4][rg] + bb));
            }
        }
    }
    __syncthreads();

    // ---- stage 2: Q (scale folded into Wq) and K; weight frags cached across mt ----
    {
        int proj = wave >> 1, nh = wave & 1;   // w0/w1: Q, w2/w3: K
        const u16* Abuf = proj ? s_oaemb : s_oemb;
        int preBase = (proj ? OFF_WK : OFF_WQ) / 8;
        u16* dst = proj ? s_bufB : s_bufA;
        const float* bias = proj ? bk_ : bq;
        float bscl = proj ? 1.f : QSCALE;
        short8 wf[16];
        #pragma unroll
        for (int n4 = 0; n4 < 4; n4++)
            #pragma unroll
            for (int kt = 0; kt < 4; kt++)
                wf[n4 * 4 + kt] = preV[preBase + ((nh * 4 + n4) * 4 + kt) * 64 + lane];
        for (int mt = 0; mt < 3; mt++) {
            short8 xa[4];
            #pragma unroll
            for (int kt = 0; kt < 4; kt++)
                xa[kt] = *(const short8*)&Abuf[(mt * 16 + l15) * LDC + kt * 32 + quad * 8];
            floatx4 acc[4] = {};
            #pragma unroll
            for (int n4 = 0; n4 < 4; n4++)
                #pragma unroll
                for (int kt = 0; kt < 4; kt++)
                    acc[n4] = __builtin_amdgcn_mfma_f32_16x16x32_bf16(xa[kt], wf[n4 * 4 + kt], acc[n4], 0, 0, 0);
            #pragma unroll
            for (int n4 = 0; n4 < 4; n4++) {
                int col = (nh * 4 + n4) * 16 + l15;
                float bb = bias[col] * bscl;
                #pragma unroll
                for (int rg = 0; rg < 4; rg++) {
                    int m = mt * 16 + quad * 4 + rg;
                    dst[m * LDC + col] = f2bf(acc[n4][rg] + bb);
                }
            }
        }
    }
    __syncthreads();

    // ---- stage 3a: masked softmax, off-diagonal only; probs stay in registers ----
    float2 prob = make_float2(0.f, 0.f);
    int e3 = 0, h3 = 0, n3 = 0, m30 = 0, m31 = 0;
    const bool attn_thread = (tid < MB * HEADS * NA);
    if (attn_thread) {
        int r = tid;
        e3 = r / (HEADS * NA); r -= e3 * HEADS * NA; h3 = r / NA; n3 = r - h3 * NA;
        m30 = (n3 == 0) ? 1 : 0;
        m31 = (n3 == 2) ? 1 : 2;
        const uint4* qp  = (const uint4*)&s_bufA[(e3 * NA + n3) * LDC + h3 * HD];
        const uint4* kp0 = (const uint4*)&s_bufB[(e3 * NA + m30) * LDC + h3 * HD];
        const uint4* kp1 = (const uint4*)&s_bufB[(e3 * NA + m31) * LDC + h3 * HD];
        float s0 = 0.f, s1 = 0.f;
        #pragma unroll
        for (int c = 0; c < 4; c++) {
            uint4 qw = qp[c], aw = kp0[c], bw = kp1[c];
            u32 qv[4] = {qw.x, qw.y, qw.z, qw.w};
            u32 av[4] = {aw.x, aw.y, aw.z, aw.w};
            u32 bv_[4] = {bw.x, bw.y, bw.z, bw.w};
            #pragma unroll
            for (int j = 0; j < 4; j++) {
                float ql = lo16f(qv[j]), qh = hi16f(qv[j]);
                s0 += ql * lo16f(av[j]) + qh * hi16f(av[j]);
                s1 += ql * lo16f(bv_[j]) + qh * hi16f(bv_[j]);
            }
        }
        float mx = fmaxf(s0, s1);
        float p0 = __expf(s0 - mx), p1 = __expf(s1 - mx);
        float inv = 1.f / (p0 + p1);
        prob = make_float2(p0 * inv, p1 * inv);
    }
    __syncthreads();

    // ---- stage 3b: V = oa_emb @ Wv + bv ; frags cached, mt loop ----
    {
        int np = wave;   // 0..3, 2 nt each
        short8 wf[8];
        #pragma unroll
        for (int n2 = 0; n2 < 2; n2++)
            #pragma unroll
            for (int kt = 0; kt < 4; kt++)
                wf[n2 * 4 + kt] = preV[OFF_WV / 8 + ((np * 2 + n2) * 4 + kt) * 64 + lane];
        for (int mt = 0; mt < 3; mt++) {
            short8 xa[4];
            #pragma unroll
            for (int kt = 0; kt < 4; kt++)
                xa[kt] = *(const short8*)&s_oaemb[(mt * 16 + l15) * LDC + kt * 32 + quad * 8];
            floatx4 acc[2] = {};
            #pragma unroll
            for (int n2 = 0; n2 < 2; n2++)
                #pragma unroll
                for (int kt = 0; kt < 4; kt++)
                    acc[n2] = __builtin_amdgcn_mfma_f32_16x16x32_bf16(xa[kt], wf[n2 * 4 + kt], acc[n2], 0, 0, 0);
            #pragma unroll
            for (int n2 = 0; n2 < 2; n2++) {
                int col = (np * 2 + n2) * 16 + l15;
                float bb = bv[col];
                #pragma unroll
                for (int rg = 0; rg < 4; rg++) {
                    int m = mt * 16 + quad * 4 + rg;
                    s_bufA[m * LDC + col] = f2bf(acc[n2][rg] + bb);
                }
            }
        }
    }
    __syncthreads();

    // ---- stage 3c: attn_out = probs @ V (probs from registers) ----
    if (attn_thread) {
        const uint4* v0p = (const uint4*)&s_bufA[(e3 * NA + m30) * LDC + h3 * HD];
        const uint4* v1p = (const uint4*)&s_bufA[(e3 * NA + m31) * LDC + h3 * HD];
        uint4* dst = (uint4*)&s_oaemb[(e3 * NA + n3) * LDC + h3 * HD];
        #pragma unroll
        for (int c = 0; c < 4; c++) {
            uint4 aw = v0p[c], bw = v1p[c], ow;
            u32 av[4] = {aw.x, aw.y, aw.z, aw.w};
            u32 bv_[4] = {bw.x, bw.y, bw.z, bw.w};
            u32 ov[4];
            #pragma unroll
            for (int j = 0; j < 4; j++) {
                float lo = prob.x * lo16f(av[j]) + prob.y * lo16f(bv_[j]);
                float hi = prob.x * hi16f(av[j]) + prob.y * hi16f(bv_[j]);
                ov[j] = pk_bf16(lo, hi);
            }
            ow.x = ov[0]; ow.y = ov[1]; ow.z = ov[2]; ow.w = ov[3];
            dst[c] = ow;
        }
    }
    __syncthreads();

    // ---- stage 4: critic layer 1, K-split concat (kt<4: o_emb, kt>=4: attn_out) ----
    for (int sj = wave; sj < 12; sj += 4) {
        int agent = sj >> 2, nq = sj & 3;
        floatx4 acc[2] = {};
        for (int kt = 0; kt < 8; kt++) {
            const u16* A = (kt < 4) ? s_oemb : s_oaemb;
            int kk = (kt & 3) * 32 + quad * 8;
            short8 a = *(const short8*)&A[(l15 * NA + agent) * LDC + kk];
            for (int n2 = 0; n2 < 2; n2++) {
                int nt = nq * 2 + n2;
                short8 b = preV[OFF_WC1 / 8 + agent * 4096 + (nt * 8 + kt) * 64 + lane];
                acc[n2] = __builtin_amdgcn_mfma_f32_16x16x32_bf16(a, b, acc[n2], 0, 0, 0);
            }
        }
        for (int n2 = 0; n2 < 2; n2++) {
            int col = (nq * 2 + n2) * 16 + l15;
            float bb = bc1[agent * HID + col];
            for (int rg = 0; rg < 4; rg++) {
                int m = quad * 4 + rg;
                s_bufB[(m * NA + agent) * LDC + col] = f2bf(leaky(acc[n2][rg] + bb));
            }
        }
    }
    __syncthreads();

    // ---- stage 5: critic layer 2 -> q_values, f32 out ----
    if (wave < NA) {
        int agent = wave;
        floatx4 acc = {};
        #pragma unroll
        for (int kt = 0; kt < 4; kt++) {
            short8 a = *(const short8*)&s_bufB[(l15 * NA + agent) * LDC + kt * 32 + quad * 8];
            short8 b = preV[OFF_WC2 / 8 + agent * 256 + kt * 64 + lane];
            acc = __builtin_amdgcn_mfma_f32_16x16x32_bf16(a, b, acc, 0, 0, 0);
        }
        int col = l15;
        if (col < ACTD) {
            float bb = bc2[agent * ACTD + col];
            #pragma unroll
            for (int rg = 0; rg < 4; rg++) {
                int m = quad * 4 + rg;
                out[((b0 + m) * NA + agent) * ACTD + col] = acc[rg] + bb;
            }
        }
    }
}

extern "C" void kernel_launch(void* const* d_in, const int* in_sizes, int n_in,
                              void* d_out, int out_size, void* d_ws, size_t ws_size,
                              hipStream_t stream) {
    const float* obs = (const float*)d_in[0];
    const float* act = (const float*)d_in[1];
    const float* Wo  = (const float*)d_in[2];
    const float* bo  = (const float*)d_in[3];
    const float* Woa = (const float*)d_in[4];
    const float* boa = (const float*)d_in[5];
    const float* Wq  = (const float*)d_in[6];
    const float* bq  = (const float*)d_in[7];
    const float* Wk  = (const float*)d_in[8];
    const float* bk  = (const float*)d_in[9];
    const float* Wv  = (const float*)d_in[10];
    const float* bv  = (const float*)d_in[11];
    const float* Wc1 = (const float*)d_in[12];
    const float* bc1 = (const float*)d_in[13];
    const float* Wc2 = (const float*)d_in[14];
    const float* bc2 = (const float*)d_in[15];
    u16* pre = (u16*)d_ws;   // needs 380928 B of workspace

    prepack_kernel<<<(PRE_TOTAL + 255) / 256, 256, 0, stream>>>(Wo, Woa, Wq, Wk, Wv, Wc1, Wc2, pre);
    fused_kernel<<<BATCH / MB, 256, 0, stream>>>(obs, act, bo, boa, bq, bk, bv, bc1, bc2, pre,
                                                 (float*)d_out);
}

// Round 6
// 261.812 us; speedup vs baseline: 1.2013x; 1.0455x over previous
//
#include <hip/hip_runtime.h>
#include <stdint.h>

typedef unsigned short u16;
typedef unsigned int u32;
typedef __attribute__((ext_vector_type(8))) short short8;
typedef __attribute__((ext_vector_type(4))) float floatx4;

#define BATCH   131072
#define NA      3
#define OBS     30
#define ACTD    9
#define HID     128
#define HEADS   4
#define HD      32
#define MB      16
#define ROWS    (MB*NA)     // 48
#define LDC     136         // padded row stride
#define LDOA    72          // oa input tile stride
#define QSCALE  0.17677669529663687f
#define NTHREADS 512

// prepacked-weight offsets in d_ws, u16 units (fragment = 64 lanes x 8 bf16)
#define OFF_WO    0
#define OFF_WOA   12288
#define OFF_WQ    36864
#define OFF_WK    53248
#define OFF_WV    69632
#define OFF_WC1   86016
#define OFF_WC2   184320
#define PRE_TOTAL 190464

__device__ __forceinline__ u16 f2bf(float f) {          // round-nearest (ties up)
    union { float f; u32 u; } v; v.f = f;
    return (u16)((v.u + 0x8000u) >> 16);
}
__device__ __forceinline__ u32 pk_bf16(float a, float b) {
    union { float f; u32 u; } x, y; x.f = a; y.f = b;
    return ((x.u + 0x8000u) >> 16) | ((y.u + 0x8000u) & 0xffff0000u);
}
__device__ __forceinline__ float lo16f(u32 w) { union { u32 u; float f; } v; v.u = w << 16; return v.f; }
__device__ __forceinline__ float hi16f(u32 w) { union { u32 u; float f; } v; v.u = w & 0xffff0000u; return v.f; }
__device__ __forceinline__ float leaky(float x) { return x >= 0.f ? x : 0.01f * x; }

// ------------- weight prepack: f32 [k][n] -> bf16 MFMA B-fragment order -------------
__global__ void prepack_kernel(const float* __restrict__ Wo,  const float* __restrict__ Woa,
                               const float* __restrict__ Wq,  const float* __restrict__ Wk,
                               const float* __restrict__ Wv,  const float* __restrict__ Wc1,
                               const float* __restrict__ Wc2, u16* __restrict__ out) {
    int i = blockIdx.x * blockDim.x + threadIdx.x;
    if (i >= PRE_TOTAL) return;
    const float* src; int K, KT, perA, base, Nsrc, Nlim; float scl = 1.f;
    if (i < OFF_WOA)      { src = Wo;  K = 30;  KT = 1; perA = 4096;  base = OFF_WO;  Nsrc = 128; Nlim = 128; }
    else if (i < OFF_WQ)  { src = Woa; K = 39;  KT = 2; perA = 8192;  base = OFF_WOA; Nsrc = 128; Nlim = 128; }
    else if (i < OFF_WK)  { src = Wq;  K = 128; KT = 4; perA = 16384; base = OFF_WQ;  Nsrc = 128; Nlim = 128; scl = QSCALE; }
    else if (i < OFF_WV)  { src = Wk;  K = 128; KT = 4; perA = 16384; base = OFF_WK;  Nsrc = 128; Nlim = 128; }
    else if (i < OFF_WC1) { src = Wv;  K = 128; KT = 4; perA = 16384; base = OFF_WV;  Nsrc = 128; Nlim = 128; }
    else if (i < OFF_WC2) { src = Wc1; K = 256; KT = 8; perA = 32768; base = OFF_WC1; Nsrc = 128; Nlim = 128; }
    else                  { src = Wc2; K = 128; KT = 4; perA = 2048;  base = OFF_WC2; Nsrc = 9;   Nlim = 9;   }
    int j = i - base;
    int agent = j / perA;
    int r = j - agent * perA;
    int e = r & 7, lane = (r >> 3) & 63, fk = r >> 9;
    int kt = fk % KT, nt = fk / KT;
    int n = nt * 16 + (lane & 15);
    int k = kt * 32 + (lane >> 4) * 8 + e;
    u16 v = 0;
    if (k < K && n < Nlim) v = f2bf(src[(agent * K + k) * Nsrc + n] * scl);
    out[i] = v;
}

// ---------------- fused forward: 512 threads (8 waves), 3 blocks/CU -> 24 waves/CU ----------------
__global__ __launch_bounds__(NTHREADS, 6) void fused_kernel(
    const float* __restrict__ obs, const float* __restrict__ act,
    const float* __restrict__ b_o, const float* __restrict__ b_oa,
    const float* __restrict__ bq,  const float* __restrict__ bk_, const float* __restrict__ bv,
    const float* __restrict__ bc1, const float* __restrict__ bc2,
    const u16* __restrict__ pre, float* __restrict__ out)
{
    __shared__ __align__(16) u16 s_mem[4 * ROWS * LDC];        // 52224 B -> 3 blk/CU
    u16* s_oemb  = s_mem;                    // o_emb (persistent)
    u16* s_oaemb = s_mem + ROWS * LDC;       // oa_emb -> attn_out
    u16* s_bufA  = s_mem + 2 * ROWS * LDC;   // oa-tile -> Q -> V
    u16* s_bufB  = s_mem + 3 * ROWS * LDC;   // K -> h

    const int tid  = threadIdx.x;
    const int wave = tid >> 6, lane = tid & 63;
    const int l15  = lane & 15, quad = lane >> 4;
    const int b0   = blockIdx.x * MB;
    const short8* preV = (const short8*)pre;

    // ---- stage 0: stage [obs|act|0] tile as packed u32 writes, layout [agent][MB][LDOA] ----
    for (int g = tid; g < ROWS * 15; g += NTHREADS) {          // obs k=0..29
        int r = g / 15, s = g - r * 15;
        int n = r / MB, bl = r - n * MB;
        const float* src = &obs[((b0 + bl) * NA + n) * OBS + 2 * s];
        *(u32*)&s_bufA[n * (MB * LDOA) + bl * LDOA + 2 * s] = pk_bf16(src[0], src[1]);
    }
    for (int g = tid; g < ROWS * 5; g += NTHREADS) {           // act k=30..38, zero k=39
        int r = g / 5, s = g - r * 5;
        int n = r / MB, bl = r - n * MB;
        const float* src = &act[((b0 + bl) * NA + n) * ACTD + 2 * s];
        float v0 = src[0], v1 = (s < 4) ? src[1] : 0.f;
        *(u32*)&s_bufA[n * (MB * LDOA) + bl * LDOA + 30 + 2 * s] = pk_bf16(v0, v1);
    }
    for (int g = tid; g < ROWS * 12; g += NTHREADS) {          // zero k=40..63
        int r = g / 12, s = g - r * 12;
        int n = r / MB, bl = r - n * MB;
        *(u32*)&s_bufA[n * (MB * LDOA) + bl * LDOA + 40 + 2 * s] = 0;
    }
    __syncthreads();

    // ---- stage 1: per-agent embeds, 24 jobs (osel, agent, nh2) over 8 waves ----
    for (int sj = wave; sj < 24; sj += 8) {
        int osel = sj / 12;             // 0: o_emb  1: oa_emb
        int rem = sj % 12, agent = rem >> 2, nh2 = rem & 3;
        int KTn = osel ? 2 : 1;
        const float* bias = osel ? b_oa : b_o;
        int preBase = osel ? (OFF_WOA / 8 + agent * 1024) : (OFF_WO / 8 + agent * 512);
        floatx4 acc[2] = {};
        for (int kt = 0; kt < KTn; kt++) {
            short8 a = *(const short8*)&s_bufA[agent * (MB * LDOA) + l15 * LDOA + kt * 32 + quad * 8];
            #pragma unroll
            for (int n2 = 0; n2 < 2; n2++) {
                int nt = nh2 * 2 + n2;
                short8 b = preV[preBase + (nt * KTn + kt) * 64 + lane];
                acc[n2] = __builtin_amdgcn_mfma_f32_16x16x32_bf16(a, b, acc[n2], 0, 0, 0);
            }
        }
        u16* dst = osel ? s_oaemb : s_oemb;
        #pragma unroll
        for (int n2 = 0; n2 < 2; n2++) {
            int col = (nh2 * 2 + n2) * 16 + l15;
            float bb = bias[agent * HID + col];
            #pragma unroll
            for (int rg = 0; rg < 4; rg++) {
                int m = quad * 4 + rg;
                dst[(m * NA + agent) * LDC + col] = f2bf(leaky(acc[n2][rg] + bb));
            }
        }
    }
    __syncthreads();

    // ---- stage 2: Q (scale folded into Wq) and K; exactly 8 jobs (proj, nh2) ----
    {
        int proj = wave >> 2, nh2 = wave & 3;   // w0-3: Q, w4-7: K
        const u16* Abuf = proj ? s_oaemb : s_oemb;
        int preBase = (proj ? OFF_WK : OFF_WQ) / 8;
        u16* dst = proj ? s_bufB : s_bufA;
        const float* bias = proj ? bk_ : bq;
        float bscl = proj ? 1.f : QSCALE;
        short8 wf[8];
        #pragma unroll
        for (int n2 = 0; n2 < 2; n2++)
            #pragma unroll
            for (int kt = 0; kt < 4; kt++)
                wf[n2 * 4 + kt] = preV[preBase + ((nh2 * 2 + n2) * 4 + kt) * 64 + lane];
        for (int mt = 0; mt < 3; mt++) {
            short8 xa[4];
            #pragma unroll
            for (int kt = 0; kt < 4; kt++)
                xa[kt] = *(const short8*)&Abuf[(mt * 16 + l15) * LDC + kt * 32 + quad * 8];
            floatx4 acc[2] = {};
            #pragma unroll
            for (int n2 = 0; n2 < 2; n2++)
                #pragma unroll
                for (int kt = 0; kt < 4; kt++)
                    acc[n2] = __builtin_amdgcn_mfma_f32_16x16x32_bf16(xa[kt], wf[n2 * 4 + kt], acc[n2], 0, 0, 0);
            #pragma unroll
            for (int n2 = 0; n2 < 2; n2++) {
                int col = (nh2 * 2 + n2) * 16 + l15;
                float bb = bias[col] * bscl;
                #pragma unroll
                for (int rg = 0; rg < 4; rg++) {
                    int m = mt * 16 + quad * 4 + rg;
                    dst[m * LDC + col] = f2bf(acc[n2][rg] + bb);
                }
            }
        }
    }
    __syncthreads();

    // ---- stage 3a: masked softmax, off-diagonal only; probs stay in registers ----
    float2 prob = make_float2(0.f, 0.f);
    int e3 = 0, h3 = 0, n3 = 0, m30 = 0, m31 = 0;
    const bool attn_thread = (tid < MB * HEADS * NA);
    if (attn_thread) {
        int r = tid;
        e3 = r / (HEADS * NA); r -= e3 * HEADS * NA; h3 = r / NA; n3 = r - h3 * NA;
        m30 = (n3 == 0) ? 1 : 0;
        m31 = (n3 == 2) ? 1 : 2;
        const uint4* qp  = (const uint4*)&s_bufA[(e3 * NA + n3) * LDC + h3 * HD];
        const uint4* kp0 = (const uint4*)&s_bufB[(e3 * NA + m30) * LDC + h3 * HD];
        const uint4* kp1 = (const uint4*)&s_bufB[(e3 * NA + m31) * LDC + h3 * HD];
        float s0 = 0.f, s1 = 0.f;
        #pragma unroll
        for (int c = 0; c < 4; c++) {
            uint4 qw = qp[c], aw = kp0[c], bw = kp1[c];
            u32 qv[4] = {qw.x, qw.y, qw.z, qw.w};
            u32 av[4] = {aw.x, aw.y, aw.z, aw.w};
            u32 bv_[4] = {bw.x, bw.y, bw.z, bw.w};
            #pragma unroll
            for (int j = 0; j < 4; j++) {
                float ql = lo16f(qv[j]), qh = hi16f(qv[j]);
                s0 += ql * lo16f(av[j]) + qh * hi16f(av[j]);
                s1 += ql * lo16f(bv_[j]) + qh * hi16f(bv_[j]);
            }
        }
        float mx = fmaxf(s0, s1);
        float p0 = __expf(s0 - mx), p1 = __expf(s1 - mx);
        float inv = 1.f / (p0 + p1);
        prob = make_float2(p0 * inv, p1 * inv);
    }
    __syncthreads();

    // ---- stage 3b: V = oa_emb @ Wv + bv ; 8 jobs (nt = wave) ----
    {
        int nt = wave;
        short8 wf[4];
        #pragma unroll
        for (int kt = 0; kt < 4; kt++)
            wf[kt] = preV[OFF_WV / 8 + (nt * 4 + kt) * 64 + lane];
        for (int mt = 0; mt < 3; mt++) {
            short8 xa[4];
            #pragma unroll
            for (int kt = 0; kt < 4; kt++)
                xa[kt] = *(const short8*)&s_oaemb[(mt * 16 + l15) * LDC + kt * 32 + quad * 8];
            floatx4 acc = {};
            #pragma unroll
            for (int kt = 0; kt < 4; kt++)
                acc = __builtin_amdgcn_mfma_f32_16x16x32_bf16(xa[kt], wf[kt], acc, 0, 0, 0);
            int col = nt * 16 + l15;
            float bb = bv[col];
            #pragma unroll
            for (int rg = 0; rg < 4; rg++) {
                int m = mt * 16 + quad * 4 + rg;
                s_bufA[m * LDC + col] = f2bf(acc[rg] + bb);
            }
        }
    }
    __syncthreads();

    // ---- stage 3c: attn_out = probs @ V (probs from registers) ----
    if (attn_thread) {
        const uint4* v0p = (const uint4*)&s_bufA[(e3 * NA + m30) * LDC + h3 * HD];
        const uint4* v1p = (const uint4*)&s_bufA[(e3 * NA + m31) * LDC + h3 * HD];
        uint4* dst = (uint4*)&s_oaemb[(e3 * NA + n3) * LDC + h3 * HD];
        #pragma unroll
        for (int c = 0; c < 4; c++) {
            uint4 aw = v0p[c], bw = v1p[c], ow;
            u32 av[4] = {aw.x, aw.y, aw.z, aw.w};
            u32 bv_[4] = {bw.x, bw.y, bw.z, bw.w};
            u32 ov[4];
            #pragma unroll
            for (int j = 0; j < 4; j++) {
                float lo = prob.x * lo16f(av[j]) + prob.y * lo16f(bv_[j]);
                float hi = prob.x * hi16f(av[j]) + prob.y * hi16f(bv_[j]);
                ov[j] = pk_bf16(lo, hi);
            }
            ow.x = ov[0]; ow.y = ov[1]; ow.z = ov[2]; ow.w = ov[3];
            dst[c] = ow;
        }
    }
    __syncthreads();

    // ---- stage 4: critic layer 1, 24 jobs (agent, nt); K-split concat ----
    for (int sj = wave; sj < 24; sj += 8) {
        int agent = sj >> 3, nt = sj & 7;
        floatx4 acc = {};
        for (int kt = 0; kt < 8; kt++) {
            const u16* A = (kt < 4) ? s_oemb : s_oaemb;
            int kk = (kt & 3) * 32 + quad * 8;
            short8 a = *(const short8*)&A[(l15 * NA + agent) * LDC + kk];
            short8 b = preV[OFF_WC1 / 8 + agent * 4096 + (nt * 8 + kt) * 64 + lane];
            acc = __builtin_amdgcn_mfma_f32_16x16x32_bf16(a, b, acc, 0, 0, 0);
        }
        int col = nt * 16 + l15;
        float bb = bc1[agent * HID + col];
        #pragma unroll
        for (int rg = 0; rg < 4; rg++) {
            int m = quad * 4 + rg;
            s_bufB[(m * NA + agent) * LDC + col] = f2bf(leaky(acc[rg] + bb));
        }
    }
    __syncthreads();

    // ---- stage 5: critic layer 2 -> q_values, f32 out ----
    if (wave < NA) {
        int agent = wave;
        floatx4 acc = {};
        #pragma unroll
        for (int kt = 0; kt < 4; kt++) {
            short8 a = *(const short8*)&s_bufB[(l15 * NA + agent) * LDC + kt * 32 + quad * 8];
            short8 b = preV[OFF_WC2 / 8 + agent * 256 + kt * 64 + lane];
            acc = __builtin_amdgcn_mfma_f32_16x16x32_bf16(a, b, acc, 0, 0, 0);
        }
        int col = l15;
        if (col < ACTD) {
            float bb = bc2[agent * ACTD + col];
            #pragma unroll
            for (int rg = 0; rg < 4; rg++) {
                int m = quad * 4 + rg;
                out[((b0 + m) * NA + agent) * ACTD + col] = acc[rg] + bb;
            }
        }
    }
}

extern "C" void kernel_launch(void* const* d_in, const int* in_sizes, int n_in,
                              void* d_out, int out_size, void* d_ws, size_t ws_size,
                              hipStream_t stream) {
    const float* obs = (const float*)d_in[0];
    const float* act = (const float*)d_in[1];
    const float* Wo  = (const float*)d_in[2];
    const float* bo  = (const float*)d_in[3];
    const float* Woa = (const float*)d_in[4];
    const float* boa = (const float*)d_in[5];
    const float* Wq  = (const float*)d_in[6];
    const float* bq  = (const float*)d_in[7];
    const float* Wk  = (const float*)d_in[8];
    const float* bk  = (const float*)d_in[9];
    const float* Wv  = (const float*)d_in[10];
    const float* bv  = (const float*)d_in[11];
    const float* Wc1 = (const float*)d_in[12];
    const float* bc1 = (const float*)d_in[13];
    const float* Wc2 = (const float*)d_in[14];
    const float* bc2 = (const float*)d_in[15];
    u16* pre = (u16*)d_ws;   // needs 380928 B of workspace

    prepack_kernel<<<(PRE_TOTAL + 255) / 256, 256, 0, stream>>>(Wo, Woa, Wq, Wk, Wv, Wc1, Wc2, pre);
    fused_kernel<<<BATCH / MB, NTHREADS, 0, stream>>>(obs, act, bo, boa, bq, bk, bv, bc1, bc2, pre,
                                                      (float*)d_out);
}